// Round 13
// baseline (308.972 us; speedup 1.0000x reference)
//
#include <hip/hip_runtime.h>
#include <math.h>

#define H 51
#define TSEEN 256
#define FUT 16
#define TTOT (TSEEN + FUT)
#define NB 8
#define THREADS 256
#define NWAVE 4
#define NBLOCKS (2048 / NB)   // 256 blocks -> 1/CU, 4 waves = 1 wave/SIMD

typedef _Float16 f16;
typedef _Float16 f16x8 __attribute__((ext_vector_type(8)));
typedef float f32x4 __attribute__((ext_vector_type(4)));

__device__ __forceinline__ float fast_rcp(float x) { return __builtin_amdgcn_rcpf(x); }
// sigmoid/tanh via v_exp; both saturate cleanly (rcp(inf)=0)
__device__ __forceinline__ float sigf(float x) {
  return fast_rcp(1.f + __expf(-x));
}
__device__ __forceinline__ float tanhf_(float x) {
  return fmaf(2.f, fast_rcp(1.f + __expf(-2.f * x)), -1.f);
}

// lane^8 within each 16-lane row: DPP row_ror:8 (VALU pipe, not LDS!)
__device__ __forceinline__ float xor8f(float v) {
  return __int_as_float(__builtin_amdgcn_mov_dpp(__float_as_int(v), 0x128, 0xf, 0xf, true));
}

#define MFMA __builtin_amdgcn_mfma_f32_16x16x32_f16

__launch_bounds__(THREADS, 1)
__global__ void lstm2_kernel(const float* __restrict__ inp,
                             const float* __restrict__ Wih1,
                             const float* __restrict__ bih1,
                             const float* __restrict__ Whh1,
                             const float* __restrict__ bhh1,
                             const float* __restrict__ Wih2,
                             const float* __restrict__ bih2,
                             const float* __restrict__ Whh2,
                             const float* __restrict__ bhh2,
                             const float* __restrict__ Wlin,
                             const float* __restrict__ blin,
                             float* __restrict__ out)
{
  // B-operand buffers in MFMA fragment layout, hi/lo packed in COLUMNS:
  // col b (0..7) = h_hi of batch b, col b+8 = h_lo of batch b.
  // [parity][ktile][lane][j]; logical (k,n): lane = n + 16*((k&31)>>3), j = k&7
  __shared__ __align__(16) f16 Bh1[2][2][64][8];
  __shared__ __align__(16) f16 Bh2[2][2][64][8];
  __shared__ __align__(16) float xs[TSEEN][NB];
  __shared__ float parts[2][NWAVE][NB];
  __shared__ float outb[TTOT][NB];   // staged outputs; flushed once at the end

  const int tid  = threadIdx.x;
  const int wv   = tid >> 6;
  const int lane = tid & 63;
  const int l15  = lane & 15;
  const int g4   = lane >> 4;
  const int bq   = l15 & 7;            // this lane's batch for the cell phase
  const bool mhi = (l15 & 8) != 0;
  const int baseb = blockIdx.x * NB;

  // ---- zero B buffers (pad slots stay 0 forever) ----
  {
    f16* b1 = &Bh1[0][0][0][0];
    f16* b2 = &Bh2[0][0][0][0];
    for (int i = tid; i < 2 * 2 * 64 * 8; i += THREADS) {
      b1[i] = (f16)0.f; b2[i] = (f16)0.f;
    }
  }
  // ---- stage inputs (coalesced per batch row) ----
  for (int i = tid; i < NB * TSEEN; i += THREADS) {
    int b = i >> 8, t = i & 255;
    xs[t][b] = inp[(size_t)(baseb + b) * TSEEN + t];
  }
  if (tid < 2 * NWAVE * NB) (&parts[0][0][0])[tid] = 0.f;

  // ---- A fragments (f16): 4 M-tiles/wave; tile m covers units 16wv+4m+slot ----
  // A layout: row = lane&15 (slot = row>>2, gate = row&3), k = 32*kt + 8*g4 + j
  f16x8 A1[4][2], A2[4][2], A3[4][2];
  #pragma unroll
  for (int m = 0; m < 4; ++m) {
    const int slotA = l15 >> 2;
    const int gA = l15 & 3;
    const int uA = 16 * wv + 4 * m + slotA;
    const bool vA = (uA < H);
    const int row = gA * H + (vA ? uA : 0);
    #pragma unroll
    for (int kt = 0; kt < 2; ++kt) {
      #pragma unroll
      for (int j = 0; j < 8; ++j) {
        const int k = 32 * kt + 8 * g4 + j;
        float w1 = 0.f, w2 = 0.f, w3 = 0.f;
        if (vA) {
          if (k < H) {
            w1 = Whh1[row * H + k];
            w2 = Wih2[row * H + k];
            w3 = Whh2[row * H + k];
          } else if (k == H) {
            w1 = Wih1[row];        // x folded in as k-slot 51 (layer 1 only)
          }
        }
        A1[m][kt][j] = (f16)w1;
        A2[m][kt][j] = (f16)w2;
        A3[m][kt][j] = (f16)w3;
      }
    }
  }

  // ---- bias C-in fragments (C layout: slot = g4, gate = reg) ----
  // Seed bias ONLY in hi columns (l15 < 8); lo columns accumulate from 0.
  f32x4 bias1[4], bias2[4];
  #pragma unroll
  for (int m = 0; m < 4; ++m) {
    const int ub = 16 * wv + 4 * m + g4;
    const bool vb = (ub < H) && (l15 < 8);
    #pragma unroll
    for (int r = 0; r < 4; ++r) {
      const int rr = r * H + (vb ? ub : 0);
      bias1[m][r] = vb ? (bih1[rr] + bhh1[rr]) : 0.f;
      bias2[m][r] = vb ? (bih2[rr] + bhh2[rr]) : 0.f;
    }
  }

  // ---- this lane's TWO cells: hi lanes own tiles {0,1}, lo lanes tiles {2,3} ----
  const int tA = mhi ? 2 : 0, tB = mhi ? 3 : 1;
  const int uCA0 = 16 * wv + 4 * tA + g4;
  const int uCB0 = 16 * wv + 4 * tB + g4;
  const bool vCA = (uCA0 < H), vCB = (uCB0 < H);
  const int uCA = vCA ? uCA0 : 0, uCB = vCB ? uCB0 : 0;
  const float wlA = vCA ? Wlin[uCA] : 0.f;
  const float wlB = vCB ? Wlin[uCB] : 0.f;
  const float bl = blin[0];
  const int wktA = uCA >> 5, wlnA = bq + 16 * ((uCA >> 3) & 3), wjA = uCA & 7;
  const int wktB = uCB >> 5, wlnB = bq + 16 * ((uCB >> 3) & 3), wjB = uCB & 7;

  float c1A = 0.f, c1B = 0.f, c2A = 0.f, c2B = 0.f;
  const f32x4 zf = {0.f, 0.f, 0.f, 0.f};

  __syncthreads();
  // x(0) into stale-parity h1 buffer, k-slot 51 (kt=1 -> lane n+32, j=3)
  if (lane < NB && wv == 0) {
    float x0 = xs[0][lane];
    f16 xh = (f16)x0;
    Bh1[1][1][lane + 32][3] = xh;                    // hi col
    Bh1[1][1][lane + 40][3] = (f16)(x0 - (float)xh); // lo col (+8)
  }
  __syncthreads();

  // ---- prologue: prefetch G1(0) from Bh1[pr=1] (h=0, x(0) at slot 51) ----
  f32x4 ac1[4];
  {
    const f16x8 p0 = *(const f16x8*)&Bh1[1][0][lane][0];
    const f16x8 p1 = *(const f16x8*)&Bh1[1][1][lane][0];
    #pragma unroll
    for (int m = 0; m < 4; ++m) {
      f32x4 c = MFMA(A1[m][0], p0, bias1[m], 0, 0, 0);
      ac1[m] = MFMA(A1[m][1], p1, c, 0, 0, 0);
    }
  }

  #pragma unroll 1
  for (int t = 0; t < TTOT; ++t) {
    const int pw = t & 1, pr = pw ^ 1;

    // ============ phase 1 (pure VALU): C1(t) for both cells ============
    // send/keep xor-8 exchange: hi lane gets lo-part of its tile, lo lane gets hi-part
    float qA0, qA1, qA2, qA3, qB0, qB1, qB2, qB3;
    {
      float s;
      s = mhi ? ac1[0][0] : ac1[2][0]; qA0 = (mhi ? ac1[2][0] : ac1[0][0]) + xor8f(s);
      s = mhi ? ac1[0][1] : ac1[2][1]; qA1 = (mhi ? ac1[2][1] : ac1[0][1]) + xor8f(s);
      s = mhi ? ac1[0][2] : ac1[2][2]; qA2 = (mhi ? ac1[2][2] : ac1[0][2]) + xor8f(s);
      s = mhi ? ac1[0][3] : ac1[2][3]; qA3 = (mhi ? ac1[2][3] : ac1[0][3]) + xor8f(s);
      s = mhi ? ac1[1][0] : ac1[3][0]; qB0 = (mhi ? ac1[3][0] : ac1[1][0]) + xor8f(s);
      s = mhi ? ac1[1][1] : ac1[3][1]; qB1 = (mhi ? ac1[3][1] : ac1[1][1]) + xor8f(s);
      s = mhi ? ac1[1][2] : ac1[3][2]; qB2 = (mhi ? ac1[3][2] : ac1[1][2]) + xor8f(s);
      s = mhi ? ac1[1][3] : ac1[3][3]; qB3 = (mhi ? ac1[3][3] : ac1[1][3]) + xor8f(s);
    }
    {
      float ivA = sigf(qA0), fvA = sigf(qA1), gvA = tanhf_(qA2), ovA = sigf(qA3);
      float ivB = sigf(qB0), fvB = sigf(qB1), gvB = tanhf_(qB2), ovB = sigf(qB3);
      c1A = fmaf(fvA, c1A, ivA * gvA);
      c1B = fmaf(fvB, c1B, ivB * gvB);
      float h1A = ovA * tanhf_(c1A);
      float h1B = ovB * tanhf_(c1B);
      if (vCA) {
        f16 hh = (f16)h1A;
        Bh1[pw][wktA][wlnA][wjA]     = hh;
        Bh1[pw][wktA][wlnA + 8][wjA] = (f16)(h1A - (float)hh);
      }
      if (vCB) {
        f16 hh = (f16)h1B;
        Bh1[pw][wktB][wlnB][wjB]     = hh;
        Bh1[pw][wktB][wlnB + 8][wjB] = (f16)(h1B - (float)hh);
      }
    }
    // x(t+1) from input, written pre-barrier (slot 51 disjoint from h-slots)
    if (t + 1 < TSEEN && lane < NB) {   // all waves write same value: benign
      float xn = xs[t + 1][lane];
      f16 xh = (f16)xn;
      Bh1[pw][1][lane + 32][3] = xh;
      Bh1[pw][1][lane + 40][3] = (f16)(xn - (float)xh);
    }
    __syncthreads();   // barrier A — the only per-step barrier (seen phase)

    // deferred output: out(t-1) for t-1 in [0, 254] -> LDS stage
    if (t >= 1 && t < TSEEN && lane < NB) {
      float s = bl + parts[pr][0][lane] + parts[pr][1][lane]
                   + parts[pr][2][lane] + parts[pr][3][lane];
      outb[t - 1][lane] = s;   // all waves write same value: benign
    }

    // ==== phase 2: G2(t) (hh + ih) AND prefetch G1(t+1) on shared frags ====
    const f16x8 b2k0 = *(const f16x8*)&Bh2[pr][0][lane][0];
    const f16x8 b2k1 = *(const f16x8*)&Bh2[pr][1][lane][0];
    const f16x8 f1k0 = *(const f16x8*)&Bh1[pw][0][lane][0];
    const f16x8 f1k1 = *(const f16x8*)&Bh1[pw][1][lane][0];

    f32x4 ac2[4];
    #pragma unroll
    for (int m = 0; m < 4; ++m) {
      f32x4 r1 = MFMA(A3[m][0], b2k0, bias2[m], 0, 0, 0);
      r1 = MFMA(A3[m][1], b2k1, r1, 0, 0, 0);
      f32x4 r2 = MFMA(A2[m][0], f1k0, zf, 0, 0, 0);
      r2 = MFMA(A2[m][1], f1k1, r2, 0, 0, 0);
      ac2[m] = r1 + r2;
      // G1(t+1) prefetch: same B fragments, layer-1 A (x col live at slot 51)
      f32x4 n = MFMA(A1[m][0], f1k0, bias1[m], 0, 0, 0);
      ac1[m] = MFMA(A1[m][1], f1k1, n, 0, 0, 0);
    }

    // recombine + cells + head
    {
      float s;
      s = mhi ? ac2[0][0] : ac2[2][0]; qA0 = (mhi ? ac2[2][0] : ac2[0][0]) + xor8f(s);
      s = mhi ? ac2[0][1] : ac2[2][1]; qA1 = (mhi ? ac2[2][1] : ac2[0][1]) + xor8f(s);
      s = mhi ? ac2[0][2] : ac2[2][2]; qA2 = (mhi ? ac2[2][2] : ac2[0][2]) + xor8f(s);
      s = mhi ? ac2[0][3] : ac2[2][3]; qA3 = (mhi ? ac2[2][3] : ac2[0][3]) + xor8f(s);
      s = mhi ? ac2[1][0] : ac2[3][0]; qB0 = (mhi ? ac2[3][0] : ac2[1][0]) + xor8f(s);
      s = mhi ? ac2[1][1] : ac2[3][1]; qB1 = (mhi ? ac2[3][1] : ac2[1][1]) + xor8f(s);
      s = mhi ? ac2[1][2] : ac2[3][2]; qB2 = (mhi ? ac2[3][2] : ac2[1][2]) + xor8f(s);
      s = mhi ? ac2[1][3] : ac2[3][3]; qB3 = (mhi ? ac2[3][3] : ac2[1][3]) + xor8f(s);
    }
    float pv;
    {
      float ivA = sigf(qA0), fvA = sigf(qA1), gvA = tanhf_(qA2), ovA = sigf(qA3);
      float ivB = sigf(qB0), fvB = sigf(qB1), gvB = tanhf_(qB2), ovB = sigf(qB3);
      c2A = fmaf(fvA, c2A, ivA * gvA);
      c2B = fmaf(fvB, c2B, ivB * gvB);
      float h2A = ovA * tanhf_(c2A);
      float h2B = ovB * tanhf_(c2B);
      pv = fmaf(wlA, h2A, wlB * h2B);
      if (vCA) {
        f16 hh = (f16)h2A;
        Bh2[pw][wktA][wlnA][wjA]     = hh;
        Bh2[pw][wktA][wlnA + 8][wjA] = (f16)(h2A - (float)hh);
      }
      if (vCB) {
        f16 hh = (f16)h2B;
        Bh2[pw][wktB][wlnB][wjB]     = hh;
        Bh2[pw][wktB][wlnB + 8][wjB] = (f16)(h2B - (float)hh);
      }
    }
    // head partial: xor8 via DPP, then xor16/32 via bpermute
    pv += xor8f(pv);
    pv += __shfl_xor(pv, 16, 64);
    pv += __shfl_xor(pv, 32, 64);
    if (lane < NB) parts[pw][wv][lane] = pv;

    // feedback phase: x(t+1) = out(t); redo G1(t+1) prefetch with fresh x
    if (t >= TSEEN - 1) {
      __syncthreads();   // publish parts[pw]
      if (lane < NB) {
        float fbv = bl + parts[pw][0][lane] + parts[pw][1][lane]
                      + parts[pw][2][lane] + parts[pw][3][lane];
        outb[t][lane] = fbv;   // all waves same value: benign
        if (t < TTOT - 1) {
          f16 xh = (f16)fbv;
          Bh1[pw][1][lane + 32][3] = xh;
          Bh1[pw][1][lane + 40][3] = (f16)(fbv - (float)xh);
        }
      }
      __syncthreads();   // slot-51 visible to all
      if (t < TTOT - 1) {
        const f16x8 g0 = *(const f16x8*)&Bh1[pw][0][lane][0];
        const f16x8 g1 = *(const f16x8*)&Bh1[pw][1][lane][0];
        #pragma unroll
        for (int m = 0; m < 4; ++m) {
          f32x4 c = MFMA(A1[m][0], g0, bias1[m], 0, 0, 0);
          ac1[m] = MFMA(A1[m][1], g1, c, 0, 0, 0);
        }
      }
    }
  }

  // ---- final flush: outb -> global (once) ----
  __syncthreads();
  for (int i = tid; i < TTOT * NB; i += THREADS) {
    int b = i / TTOT, t = i - b * TTOT;
    out[(size_t)(baseb + b) * TTOT + t] = outb[t][b];
  }
}

extern "C" void kernel_launch(void* const* d_in, const int* in_sizes, int n_in,
                              void* d_out, int out_size, void* d_ws, size_t ws_size,
                              hipStream_t stream) {
  (void)in_sizes; (void)n_in; (void)d_ws; (void)ws_size; (void)out_size;
  const float* inp  = (const float*)d_in[0];
  const float* Wih1 = (const float*)d_in[1];
  const float* bih1 = (const float*)d_in[2];
  const float* Whh1 = (const float*)d_in[3];
  const float* bhh1 = (const float*)d_in[4];
  const float* Wih2 = (const float*)d_in[5];
  const float* bih2 = (const float*)d_in[6];
  const float* Whh2 = (const float*)d_in[7];
  const float* bhh2 = (const float*)d_in[8];
  const float* Wlin = (const float*)d_in[9];
  const float* blin = (const float*)d_in[10];
  float* outp = (float*)d_out;

  lstm2_kernel<<<NBLOCKS, THREADS, 0, stream>>>(
      inp, Wih1, bih1, Whh1, bhh1, Wih2, bih2, Whh2, bhh2, Wlin, blin, outp);
}

// Round 14
// 237.516 us; speedup vs baseline: 1.3009x; 1.3009x over previous
//
#include <hip/hip_runtime.h>
#include <math.h>

#define H 51
#define TSEEN 256
#define FUT 16
#define TTOT (TSEEN + FUT)
#define NB 8
#define THREADS 512
#define NWAVE 8
#define UPW 7                 // units per wave (8*7=56 >= 51)
#define NBLOCKS (2048 / NB)   // 256 blocks -> 1/CU, 8 waves = 2 waves/SIMD

typedef _Float16 f16;
typedef _Float16 f16x8 __attribute__((ext_vector_type(8)));
typedef float f32x4 __attribute__((ext_vector_type(4)));

__device__ __forceinline__ float fast_rcp(float x) { return __builtin_amdgcn_rcpf(x); }
// sigmoid/tanh via v_exp; both saturate cleanly (rcp(inf)=0)
__device__ __forceinline__ float sigf(float x) {
  return fast_rcp(1.f + __expf(-x));
}
__device__ __forceinline__ float tanhf_(float x) {
  return fmaf(2.f, fast_rcp(1.f + __expf(-2.f * x)), -1.f);
}

// lane^8 within each 16-lane row: DPP row_ror:8 (VALU pipe, not LDS!)
__device__ __forceinline__ float xor8f(float v) {
  return __int_as_float(__builtin_amdgcn_mov_dpp(__float_as_int(v), 0x128, 0xf, 0xf, true));
}

#define MFMA __builtin_amdgcn_mfma_f32_16x16x32_f16

// hi+lo recombine in send/keep form: lane b keeps tile0-hi, receives tile0-lo
// from lane b+8; lane b+8 keeps tile1-lo, receives tile1-hi from lane b.
__device__ __forceinline__ void recomb(const f32x4& a0, const f32x4& a1, bool mhi,
                                       float& q0, float& q1, float& q2, float& q3) {
  float s0 = mhi ? a0[0] : a1[0];
  float s1 = mhi ? a0[1] : a1[1];
  float s2 = mhi ? a0[2] : a1[2];
  float s3 = mhi ? a0[3] : a1[3];
  float k0 = mhi ? a1[0] : a0[0];
  float k1 = mhi ? a1[1] : a0[1];
  float k2 = mhi ? a1[2] : a0[2];
  float k3 = mhi ? a1[3] : a0[3];
  q0 = k0 + xor8f(s0);
  q1 = k1 + xor8f(s1);
  q2 = k2 + xor8f(s2);
  q3 = k3 + xor8f(s3);
}

__launch_bounds__(THREADS, 2)
__global__ void lstm2_kernel(const float* __restrict__ inp,
                             const float* __restrict__ Wih1,
                             const float* __restrict__ bih1,
                             const float* __restrict__ Whh1,
                             const float* __restrict__ bhh1,
                             const float* __restrict__ Wih2,
                             const float* __restrict__ bih2,
                             const float* __restrict__ Whh2,
                             const float* __restrict__ bhh2,
                             const float* __restrict__ Wlin,
                             const float* __restrict__ blin,
                             float* __restrict__ out)
{
  // B-operand buffers in MFMA fragment layout, hi/lo packed in COLUMNS:
  // col b (0..7) = h_hi of batch b, col b+8 = h_lo of batch b.
  // [parity][ktile][lane][j]; logical (k,n): lane = n + 16*((k&31)>>3), j = k&7
  __shared__ __align__(16) f16 Bh1[2][2][64][8];
  __shared__ __align__(16) f16 Bh2[2][2][64][8];
  __shared__ __align__(16) float xs[TSEEN][NB];
  __shared__ float parts[2][NWAVE][NB];
  __shared__ float outb[TTOT][NB];   // staged outputs; flushed once at the end

  const int tid  = threadIdx.x;
  const int wv   = tid >> 6;
  const int lane = tid & 63;
  const int l15  = lane & 15;
  const int g4   = lane >> 4;
  const int bq   = l15 & 7;            // this lane's batch for the cell phase
  const bool mhi = (l15 & 8) != 0;     // takes the m=1 tile after recombine
  const int baseb = blockIdx.x * NB;

  // ---- zero B buffers (pad slots stay 0 forever) ----
  {
    f16* b1 = &Bh1[0][0][0][0];
    f16* b2 = &Bh2[0][0][0][0];
    for (int i = tid; i < 2 * 2 * 64 * 8; i += THREADS) {
      b1[i] = (f16)0.f; b2[i] = (f16)0.f;
    }
  }
  // ---- stage inputs (coalesced per batch row) ----
  for (int i = tid; i < NB * TSEEN; i += THREADS) {
    int b = i >> 8, t = i & 255;
    xs[t][b] = inp[(size_t)(baseb + b) * TSEEN + t];
  }
  if (tid < 2 * NWAVE * NB) (&parts[0][0][0])[tid] = 0.f;

  // ---- A fragments (f16), virtual row v = 4*unit_slot + gate; 2 M-tiles/wave ----
  f16x8 A1[2][2], A2[2][2], A3[2][2];
  #pragma unroll
  for (int m = 0; m < 2; ++m) {
    const int slotA = 4 * m + (l15 >> 2);
    const int uA = UPW * wv + slotA;
    const int gA = l15 & 3;
    const bool vA = (slotA < UPW) && (uA < H);
    const int row = gA * H + (vA ? uA : 0);
    #pragma unroll
    for (int kt = 0; kt < 2; ++kt) {
      #pragma unroll
      for (int j = 0; j < 8; ++j) {
        const int k = 32 * kt + 8 * g4 + j;
        float w1 = 0.f, w2 = 0.f, w3 = 0.f;
        if (vA) {
          if (k < H) {
            w1 = Whh1[row * H + k];
            w2 = Wih2[row * H + k];
            w3 = Whh2[row * H + k];
          } else if (k == H) {
            w1 = Wih1[row];        // x folded in as k-slot 51 (layer 1 only)
          }
        }
        A1[m][kt][j] = (f16)w1;
        A2[m][kt][j] = (f16)w2;
        A3[m][kt][j] = (f16)w3;
      }
    }
  }

  // ---- bias C-in fragments (C layout: unit_slot = 4m+g4, gate = reg) ----
  // Seed bias ONLY in hi columns (l15 < 8); lo columns accumulate from 0.
  f32x4 bias1[2], bias2[2];
  #pragma unroll
  for (int m = 0; m < 2; ++m) {
    const int ulC = 4 * m + g4;
    const int u = UPW * wv + ulC;
    const bool v = (ulC < UPW) && (u < H) && (l15 < 8);
    #pragma unroll
    for (int r = 0; r < 4; ++r) {
      const int rr = r * H + (v ? u : 0);
      bias1[m][r] = v ? (bih1[rr] + bhh1[rr]) : 0.f;
      bias2[m][r] = v ? (bih2[rr] + bhh2[rr]) : 0.f;
    }
  }

  // ---- this lane's cell: unit slot (mhi? 4:0)+g4, batch bq ----
  const int slotC = (mhi ? 4 : 0) + g4;
  const int uC0 = UPW * wv + slotC;
  const bool vC = (slotC < UPW) && (uC0 < H);
  const int uC = vC ? uC0 : 0;
  const float wl = vC ? Wlin[uC] : 0.f;
  const float bl = blin[0];
  const int wkt = uC >> 5;                    // h-frag write address for (uC,bq)
  const int wln = bq + 16 * ((uC >> 3) & 3);  // hi col; lo col = wln + 8
  const int wj  = uC & 7;

  float c1 = 0.f, c2 = 0.f;
  const f32x4 zf = {0.f, 0.f, 0.f, 0.f};

  __syncthreads();
  // x(0) into stale-parity h1 buffer, k-slot 51 (kt=1 -> lane n+32, j=3)
  if (tid < NB) {
    float x0 = xs[0][tid];
    f16 xh = (f16)x0;
    Bh1[1][1][tid + 32][3] = xh;                    // hi col
    Bh1[1][1][tid + 40][3] = (f16)(x0 - (float)xh); // lo col (+8)
  }
  __syncthreads();

  // ---- prologue: prefetch G1(0) from Bh1[pr=1] (h=0, x(0) at slot 51) ----
  f32x4 ac1[2];
  f32x4 ac2s[2];   // deferred G2 accumulators (produced P2(t), consumed P1(t+1))
  {
    const f16x8 p0 = *(const f16x8*)&Bh1[1][0][lane][0];
    const f16x8 p1 = *(const f16x8*)&Bh1[1][1][lane][0];
    #pragma unroll
    for (int m = 0; m < 2; ++m) {
      f32x4 c = MFMA(A1[m][0], p0, bias1[m], 0, 0, 0);
      ac1[m] = MFMA(A1[m][1], p1, c, 0, 0, 0);
    }
  }

  #pragma unroll 1
  for (int t = 0; t < TTOT; ++t) {
    const int pw = t & 1, pr = pw ^ 1;

    // ===== phase 1 (pure VALU): C2(t-1) [deferred] + C1(t), interleaved =====
    float q0, q1, q2, q3;
    // resolve deferred C2(t-1): deferred iff t-1 < TSEEN-1
    if (t >= 1 && t <= TSEEN - 1) {
      recomb(ac2s[0], ac2s[1], mhi, q0, q1, q2, q3);
      float iv = sigf(q0), fv = sigf(q1);
      float gv = tanhf_(q2), ov = sigf(q3);
      c2 = fmaf(fv, c2, iv * gv);
      float h2n = ov * tanhf_(c2);
      float pv = wl * h2n;
      if (vC) {
        f16 hh = (f16)h2n;
        Bh2[pr][wkt][wln][wj]     = hh;    // h2(t-1) -> parity pw(t-1) = pr
        Bh2[pr][wkt][wln + 8][wj] = (f16)(h2n - (float)hh);
      }
      pv += xor8f(pv);
      pv += __shfl_xor(pv, 16, 64);
      pv += __shfl_xor(pv, 32, 64);
      if (lane < NB) parts[pr][wv][lane] = pv;   // parts for step t-1
    }
    // C1(t) from prefetched ac1
    recomb(ac1[0], ac1[1], mhi, q0, q1, q2, q3);
    {
      float iv = sigf(q0), fv = sigf(q1);
      float gv = tanhf_(q2), ov = sigf(q3);
      c1 = fmaf(fv, c1, iv * gv);
      float h1n = ov * tanhf_(c1);
      if (vC) {
        f16 hh = (f16)h1n;
        Bh1[pw][wkt][wln][wj]     = hh;
        Bh1[pw][wkt][wln + 8][wj] = (f16)(h1n - (float)hh);
      }
    }
    // x(t+1) from input, written pre-barrier (slot 51 disjoint from h-slots)
    if (t + 1 < TSEEN && tid < NB) {
      float xn = xs[t + 1][tid];
      f16 xh = (f16)xn;
      Bh1[pw][1][tid + 32][3] = xh;
      Bh1[pw][1][tid + 40][3] = (f16)(xn - (float)xh);
    }
    __syncthreads();   // barrier A — the only per-step barrier (seen phase)

    // deferred output: out(t-1) for t-1 in [0, 254] -> LDS stage
    if (t >= 1 && t < TSEEN && tid < NB) {
      float s = bl;
      #pragma unroll
      for (int w = 0; w < NWAVE; ++w) s += parts[pr][w][tid];
      outb[t - 1][tid] = s;
    }

    // ===== phase 2: MFMA only (seen steps): G2(t) deferred + G1(t+1) prefetch =====
    const f16x8 b2k0 = *(const f16x8*)&Bh2[pr][0][lane][0];
    const f16x8 b2k1 = *(const f16x8*)&Bh2[pr][1][lane][0];
    const f16x8 f1k0 = *(const f16x8*)&Bh1[pw][0][lane][0];
    const f16x8 f1k1 = *(const f16x8*)&Bh1[pw][1][lane][0];

    if (t < TSEEN - 1) {
      // deferred mode: keep ac2 in regs; no cell work here
      #pragma unroll
      for (int m = 0; m < 2; ++m) {
        f32x4 r1 = MFMA(A3[m][0], b2k0, bias2[m], 0, 0, 0);
        r1 = MFMA(A3[m][1], b2k1, r1, 0, 0, 0);
        f32x4 r2 = MFMA(A2[m][0], f1k0, zf, 0, 0, 0);
        r2 = MFMA(A2[m][1], f1k1, r2, 0, 0, 0);
        ac2s[m] = r1 + r2;
        // G1(t+1) prefetch: same B fragments, layer-1 A (x col at slot 51)
        f32x4 n = MFMA(A1[m][0], f1k0, bias1[m], 0, 0, 0);
        ac1[m] = MFMA(A1[m][1], f1k1, n, 0, 0, 0);
      }
    } else {
      // inline mode (feedback turnaround, t >= TSEEN-1): r11 path verbatim
      f32x4 ac2[2];
      #pragma unroll
      for (int m = 0; m < 2; ++m) {
        f32x4 r1 = MFMA(A3[m][0], b2k0, bias2[m], 0, 0, 0);
        r1 = MFMA(A3[m][1], b2k1, r1, 0, 0, 0);
        f32x4 r2 = MFMA(A2[m][0], f1k0, zf, 0, 0, 0);
        r2 = MFMA(A2[m][1], f1k1, r2, 0, 0, 0);
        ac2[m] = r1 + r2;
      }
      recomb(ac2[0], ac2[1], mhi, q0, q1, q2, q3);
      float pv;
      {
        float iv = sigf(q0), fv = sigf(q1);
        float gv = tanhf_(q2), ov = sigf(q3);
        c2 = fmaf(fv, c2, iv * gv);
        float h2n = ov * tanhf_(c2);
        pv = wl * h2n;
        if (vC) {
          f16 hh = (f16)h2n;
          Bh2[pw][wkt][wln][wj]     = hh;
          Bh2[pw][wkt][wln + 8][wj] = (f16)(h2n - (float)hh);
        }
      }
      pv += xor8f(pv);
      pv += __shfl_xor(pv, 16, 64);
      pv += __shfl_xor(pv, 32, 64);
      if (lane < NB) parts[pw][wv][lane] = pv;

      __syncthreads();   // publish parts[pw]
      if (tid < NB) {
        float fbv = bl;
        #pragma unroll
        for (int w = 0; w < NWAVE; ++w) fbv += parts[pw][w][tid];
        outb[t][tid] = fbv;
        if (t < TTOT - 1) {
          f16 xh = (f16)fbv;
          Bh1[pw][1][tid + 32][3] = xh;
          Bh1[pw][1][tid + 40][3] = (f16)(fbv - (float)xh);
        }
      }
      __syncthreads();   // slot-51 visible to all
      if (t < TTOT - 1) {
        const f16x8 g0 = *(const f16x8*)&Bh1[pw][0][lane][0];
        const f16x8 g1 = *(const f16x8*)&Bh1[pw][1][lane][0];
        #pragma unroll
        for (int m = 0; m < 2; ++m) {
          f32x4 c = MFMA(A1[m][0], g0, bias1[m], 0, 0, 0);
          ac1[m] = MFMA(A1[m][1], g1, c, 0, 0, 0);
        }
      }
    }
  }

  // ---- final flush: outb -> global (once) ----
  __syncthreads();
  for (int i = tid; i < TTOT * NB; i += THREADS) {
    int b = i / TTOT, t = i - b * TTOT;
    out[(size_t)(baseb + b) * TTOT + t] = outb[t][b];
  }
}

extern "C" void kernel_launch(void* const* d_in, const int* in_sizes, int n_in,
                              void* d_out, int out_size, void* d_ws, size_t ws_size,
                              hipStream_t stream) {
  (void)in_sizes; (void)n_in; (void)d_ws; (void)ws_size; (void)out_size;
  const float* inp  = (const float*)d_in[0];
  const float* Wih1 = (const float*)d_in[1];
  const float* bih1 = (const float*)d_in[2];
  const float* Whh1 = (const float*)d_in[3];
  const float* bhh1 = (const float*)d_in[4];
  const float* Wih2 = (const float*)d_in[5];
  const float* bih2 = (const float*)d_in[6];
  const float* Whh2 = (const float*)d_in[7];
  const float* bhh2 = (const float*)d_in[8];
  const float* Wlin = (const float*)d_in[9];
  const float* blin = (const float*)d_in[10];
  float* outp = (float*)d_out;

  lstm2_kernel<<<NBLOCKS, THREADS, 0, stream>>>(
      inp, Wih1, bih1, Whh1, bhh1, Wih2, bih2, Whh2, bhh2, Wlin, blin, outp);
}